// Round 1
// baseline (2820.130 us; speedup 1.0000x reference)
//
#include <hip/hip_runtime.h>
#include <math.h>

#define D     128
#define TM    64
#define TN    64
#define NSEG  32
#define KTOP  10

// Insert (s,v) into sorted-ascending 10-entry register list. Caller guarantees s < ls[9].
// Constant indexing only (unrolled) so lists stay in VGPRs.
__device__ __forceinline__ void insert10(float s, float v, float ls[KTOP], float lw[KTOP]) {
    ls[9] = s; lw[9] = v;
#pragma unroll
    for (int p = 9; p > 0; --p) {
        bool sw = ls[p] < ls[p - 1];
        float ts = sw ? ls[p - 1] : ls[p];
        float tl = sw ? ls[p]     : ls[p - 1];
        float tv = sw ? lw[p - 1] : lw[p];
        float tu = sw ? lw[p]     : lw[p - 1];
        ls[p] = ts; ls[p - 1] = tl;
        lw[p] = tv; lw[p - 1] = tu;
    }
}

// out[row] = sum(X[row]^2) - (useW ? w[row] : 0).  One wave (64 lanes) per row, d=128 = 64 float2.
__global__ void rowsum2_kernel(const float* __restrict__ X, const float* __restrict__ w,
                               float* __restrict__ out, int nrows, int useW) {
    int wave = threadIdx.x >> 6;
    int lane = threadIdx.x & 63;
    int row = blockIdx.x * 4 + wave;
    if (row >= nrows) return;
    float2 v = ((const float2*)X)[(size_t)row * 64 + lane];
    float s = v.x * v.x + v.y * v.y;
#pragma unroll
    for (int o = 32; o > 0; o >>= 1) s += __shfl_down(s, o, 64);
    if (lane == 0) out[row] = useW ? (s - w[row]) : s;
}

// Main: per (query-tile, segment) block: fp32 GEMM tile + fused per-query top-10 of
// s = x2w[j] - 2*q.x.  Emits per-segment top-10 (s,w) pairs per query.
__launch_bounds__(256, 2)
__global__ void nd_main(const float* __restrict__ Xt, const float* __restrict__ X,
                        const float* __restrict__ w,  const float* __restrict__ x2w,
                        float2* __restrict__ topbuf, int m, int n) {
    __shared__ __align__(16) float As[TM * D];      // 32 KB, [q][128] row-major
    __shared__ __align__(16) float Bs[TN * 36];     // 9 KB,  [c][36] (32 cols used, pad->36)
    __shared__ __align__(16) float pool[TM * 80];   // 20 KB: Ssh[64][65] during tiles, Msh[64][40] f2 at end
    __shared__ float x2s[TN];
    __shared__ float wsh[TN];

    const int t = threadIdx.x;
    const int qbase = blockIdx.x * TM;
    const int seg = blockIdx.y;
    const int segSize = (n + NSEG - 1) / NSEG;
    const int segStart = seg * segSize;
    const int segEnd = min(segStart + segSize, n);
    const int ntiles = (segEnd - segStart + TN - 1) / TN;

    // Stage A (queries) once: 64 rows x 32 float4
    const float4* Xt4 = (const float4*)Xt;
    float4* As4 = (float4*)As;
#pragma unroll
    for (int r = 0; r < 8; ++r) {
        int f = t + 256 * r;
        int q = f >> 5, c4 = f & 31;
        int qq = min(qbase + q, m - 1);
        As4[q * 32 + c4] = Xt4[(size_t)qq * 32 + c4];
    }

    const int ty = t >> 4, tx = t & 15;      // compute mapping: 4 queries x 4 cands each
    const int qsub = t >> 2, sub = t & 3;    // topk mapping: 4 threads per query

    float ls[KTOP], lw[KTOP];
#pragma unroll
    for (int e = 0; e < KTOP; ++e) { ls[e] = INFINITY; lw[e] = 0.f; }

    const float4* X4 = (const float4*)X;
    float4* Bs4 = (float4*)Bs;

    for (int tile = 0; tile < ntiles; ++tile) {
        const int base = segStart + tile * TN;
        float acc[4][4];
#pragma unroll
        for (int i = 0; i < 4; ++i)
#pragma unroll
            for (int j = 0; j < 4; ++j) acc[i][j] = 0.f;

        for (int dchunk = 0; dchunk < 4; ++dchunk) {
            __syncthreads();   // prev readers of Bs/pool done
            // stage B chunk: 64 cand rows x 8 float4 (32 floats of d)
#pragma unroll
            for (int r = 0; r < 2; ++r) {
                int f = t + 256 * r;
                int c = f >> 3, c4 = f & 7;
                int jj = min(base + c, n - 1);
                Bs4[c * 9 + c4] = X4[(size_t)jj * 32 + dchunk * 8 + c4];
            }
            if (dchunk == 0 && t < TN) {
                int jj = min(base + t, n - 1);
                x2s[t] = x2w[jj];
                wsh[t] = w[jj];
            }
            __syncthreads();
            // compute: 8 groups of 4 d-elements
#pragma unroll
            for (int d4 = 0; d4 < 8; ++d4) {
                float4 a[4], b[4];
#pragma unroll
                for (int i = 0; i < 4; ++i) a[i] = As4[(ty * 4 + i) * 32 + dchunk * 8 + d4];
#pragma unroll
                for (int j = 0; j < 4; ++j) b[j] = Bs4[(tx * 4 + j) * 9 + d4];
#pragma unroll
                for (int i = 0; i < 4; ++i)
#pragma unroll
                    for (int j = 0; j < 4; ++j)
                        acc[i][j] = fmaf(a[i].x, b[j].x,
                                    fmaf(a[i].y, b[j].y,
                                    fmaf(a[i].z, b[j].z,
                                    fmaf(a[i].w, b[j].w, acc[i][j]))));
            }
        }
        __syncthreads();
        // write s-tile to pool (Ssh[64][65]); invalid candidates -> +inf
#pragma unroll
        for (int i = 0; i < 4; ++i)
#pragma unroll
            for (int j = 0; j < 4; ++j) {
                int c = tx * 4 + j;
                int jj = base + c;
                float sv = (jj < segEnd) ? fmaf(-2.0f, acc[i][j], x2s[c]) : INFINITY;
                pool[(ty * 4 + i) * 65 + c] = sv;
            }
        __syncthreads();
        // top-k scan: thread owns query qsub, candidates [sub*16, sub*16+16)
#pragma unroll
        for (int i2 = 0; i2 < 16; ++i2) {
            int c = sub * 16 + i2;
            float s = pool[qsub * 65 + c];
            if (s < ls[9]) insert10(s, wsh[c], ls, lw);
        }
    }

    // merge 4 per-thread lists per query -> per-segment top-10
    __syncthreads();
    float2* Msh = (float2*)pool;  // 64 x 40 float2 = 20 KB
#pragma unroll
    for (int e = 0; e < KTOP; ++e) Msh[qsub * 40 + sub * 10 + e] = make_float2(ls[e], lw[e]);
    __syncthreads();
    if (t < TM) {
        float ms[KTOP], mw[KTOP];
#pragma unroll
        for (int e = 0; e < KTOP; ++e) { ms[e] = INFINITY; mw[e] = 0.f; }
        for (int x = 0; x < 4 * KTOP; ++x) {
            float2 v = Msh[t * 40 + x];
            if (v.x < ms[9]) insert10(v.x, v.y, ms, mw);
        }
        size_t off = ((size_t)seg * m + (qbase + t)) * KTOP;
#pragma unroll
        for (int e = 0; e < KTOP; ++e) topbuf[off + e] = make_float2(ms[e], mw[e]);
    }
}

// Final: merge NSEG per-segment lists per query, compute act = w - sqrt(q2 + s + w), take max.
__global__ void nd_merge(const float2* __restrict__ topbuf, const float* __restrict__ q2buf,
                         float* __restrict__ out, int m) {
    int q = blockIdx.x * blockDim.x + threadIdx.x;
    if (q >= m) return;
    float ls[KTOP], lw[KTOP];
#pragma unroll
    for (int e = 0; e < KTOP; ++e) { ls[e] = INFINITY; lw[e] = 0.f; }
    for (int seg = 0; seg < NSEG; ++seg) {
        size_t off = ((size_t)seg * m + q) * KTOP;
#pragma unroll
        for (int e = 0; e < KTOP; ++e) {
            float2 v = topbuf[off + e];
            if (v.x < ls[9]) insert10(v.x, v.y, ls, lw);
        }
    }
    float q2v = q2buf[q];
    float mx = -INFINITY;
#pragma unroll
    for (int e = 0; e < KTOP; ++e) {
        if (ls[e] < 1e30f) {
            float d2 = fmaxf(q2v + ls[e] + lw[e], 0.f);
            mx = fmaxf(mx, lw[e] - sqrtf(d2));
        }
    }
    out[q] = mx;
}

extern "C" void kernel_launch(void* const* d_in, const int* in_sizes, int n_in,
                              void* d_out, int out_size, void* d_ws, size_t ws_size,
                              hipStream_t stream) {
    const float* Xt = (const float*)d_in[0];
    const float* X  = (const float*)d_in[1];
    const float* w  = (const float*)d_in[2];
    const int m = in_sizes[0] / D;   // 2048
    const int n = in_sizes[1] / D;   // 100000

    float* ws_f  = (float*)d_ws;
    float* x2w   = ws_f;                                   // n floats
    float* q2    = ws_f + ((n + 255) & ~255);              // m floats
    float2* topbuf = (float2*)(q2 + ((m + 255) & ~255));   // m*NSEG*KTOP float2 (~5.2 MB)

    rowsum2_kernel<<<(n + 3) / 4, 256, 0, stream>>>(X, w, x2w, n, 1);
    rowsum2_kernel<<<(m + 3) / 4, 256, 0, stream>>>(Xt, w, q2, m, 0);

    dim3 grid((m + TM - 1) / TM, NSEG);
    nd_main<<<grid, 256, 0, stream>>>(Xt, X, w, x2w, topbuf, m, n);

    nd_merge<<<(m + 255) / 256, 256, 0, stream>>>(topbuf, q2, (float*)d_out, m);
}

// Round 2
// 347.170 us; speedup vs baseline: 8.1232x; 8.1232x over previous
//
#include <hip/hip_runtime.h>
#include <math.h>

typedef __attribute__((ext_vector_type(8))) short short8;
typedef __attribute__((ext_vector_type(16))) float f32x16;

#define D      128
#define NSEG   64
#define TILE_C 64
#define KTOP   10
#define CAP    64
#define DELTA  3.0f

// ---------- helpers ----------
__device__ __forceinline__ ushort f2bf(float f) {
    uint u = __float_as_uint(f);
    uint r = (u + 0x7FFFu + ((u >> 16) & 1u)) >> 16;
    return (ushort)r;
}

__device__ __forceinline__ void insert10(float s, float v, float ls[KTOP], float lw[KTOP]) {
    ls[9] = s; lw[9] = v;
#pragma unroll
    for (int p = 9; p > 0; --p) {
        bool sw = ls[p] < ls[p - 1];
        float ts = sw ? ls[p - 1] : ls[p];
        float tl = sw ? ls[p]     : ls[p - 1];
        float tv = sw ? lw[p - 1] : lw[p];
        float tu = sw ? lw[p]     : lw[p - 1];
        ls[p] = ts; ls[p - 1] = tl;
        lw[p] = tv; lw[p - 1] = tu;
    }
}

// ---------- prep: fp32 row -> bf16 row, row-sum-of-squares (minus w), x2w hi/lo pack ----------
// one wave per row, 4 rows per block
__global__ void prep_kernel(const float* __restrict__ Xf, const float* __restrict__ w,
                            ushort* __restrict__ Xb, uint* __restrict__ x2p,
                            float* __restrict__ x2wf, int nrows, int useW) {
    int wave = threadIdx.x >> 6, lane = threadIdx.x & 63;
    int row = blockIdx.x * 4 + wave;
    if (row >= nrows) return;
    float2 v = ((const float2*)Xf)[(size_t)row * 64 + lane];
    ushort2 bv = make_ushort2(f2bf(v.x), f2bf(v.y));
    ((ushort2*)Xb)[(size_t)row * 64 + lane] = bv;
    float s = v.x * v.x + v.y * v.y;
#pragma unroll
    for (int o = 32; o; o >>= 1) s += __shfl_xor(s, o, 64);
    if (lane == 0) {
        float x2w = useW ? (s - w[row]) : s;
        x2wf[row] = x2w;
        if (x2p) {
            ushort h = f2bf(x2w);
            float hf = __uint_as_float(((uint)h) << 16);
            ushort lo = f2bf(x2w - hf);
            x2p[row] = (uint)h | ((uint)lo << 16);
        }
    }
}

// ---------- swizzled LDS A-tile access: unit = 16B = 8 bf16, pitch 24 units/row ----------
__device__ __forceinline__ short8 ldsA(const ushort* As, int c, int kb) {
    return *(const short8*)&As[(c * 24 + (kb ^ (c & 7))) * 8];
}

__device__ __forceinline__ void emit_cand(int q, int c, int* cnt, int* buf) {
    int pos = atomicAdd(&cnt[q], 1);
    if (pos < CAP) buf[q * CAP + pos] = c;
}

// ---------- main GEMM pass (PASS 1: stream-min, PASS 2: filter-emit) ----------
// block = 256 thr = 4 waves; block covers 256 queries x one candidate segment.
// wave tile: 64 cands x 64 queries via 4x v_mfma_f32_32x32x16_bf16 per k-step.
// A (cands) staged in swizzled LDS; B (queries) fragments preloaded in registers.
// K = 130 (128 dims + x2w hi/lo with B-coef -0.5) padded to 144 (9 k-steps).
template<int PASS>
__global__ __launch_bounds__(256, 2) void nd_pass(
        const ushort* __restrict__ Xb, const ushort* __restrict__ Xtb,
        const uint* __restrict__ x2p, const float* __restrict__ tau,
        float* __restrict__ minbuf, int* __restrict__ cnt, int* __restrict__ buf,
        int m, int n) {
    __shared__ __align__(16) ushort As[TILE_C * 24 * 8];   // 24.6 KB

    const int t = threadIdx.x;
    const int l = t & 63, wv = t >> 6;
    const int seg = blockIdx.y;
    const int qbase = blockIdx.x * 256;
    const int segSize = (n + NSEG - 1) / NSEG;
    const int segStart = seg * segSize;
    const int segEnd = min(segStart + segSize, n);
    const int ntiles = (segEnd - segStart + TILE_C - 1) / TILE_C;

    const int q0 = qbase + wv * 64 + (l & 31);   // query for qb=0 (qb=1 -> +32)

    // preload B fragments: [kstep][qb], 8 consecutive k per lane-half
    short8 Bf[9][2];
#pragma unroll
    for (int s = 0; s < 8; ++s)
#pragma unroll
        for (int qb = 0; qb < 2; ++qb)
            Bf[s][qb] = *(const short8*)(Xtb + (size_t)(q0 + qb * 32) * D + s * 16 + (l >> 5) * 8);
    {   // kstep 8: k=128,129 carry coefficient -0.5 (lane-half 0 only), rest zero
        short8 z = (short8)(short)0;
        if (l < 32) { z[0] = (short)0xBF00; z[1] = (short)0xBF00; }
        Bf[8][0] = z; Bf[8][1] = z;
    }

    float tq0 = 0.f, tq1 = 0.f;
    if (PASS == 2) { tq0 = tau[q0]; tq1 = tau[q0 + 32]; }
    float mn0 = INFINITY, mn1 = INFINITY;

    for (int tile = 0; tile < ntiles; ++tile) {
        const int base = segStart + tile * TILE_C;
        __syncthreads();
        // stage A tile: 64 cand rows x 16 units (k 0..127), swizzled
        const uint4* Xg = (const uint4*)Xb;
#pragma unroll
        for (int it = 0; it < 4; ++it) {
            int ff = t + 256 * it;
            int c = ff >> 4, kb = ff & 15;
            int rr = min(base + c, n - 1);
            uint4 v = Xg[(size_t)rr * 16 + kb];
            *(uint4*)&As[(c * 24 + (kb ^ (c & 7))) * 8] = v;
        }
        // units kb=16 ([x2w_hi, x2w_lo, 0..]) and kb=17 (zeros; must not be NaN garbage)
        if (t < 128) {
            int c = t & 63;
            int kb = 16 + (t >> 6);
            uint hl = (t < 64) ? x2p[min(base + c, n - 1)] : 0u;
            *(uint4*)&As[(c * 24 + (kb ^ (c & 7))) * 8] = make_uint4(hl, 0u, 0u, 0u);
        }
        __syncthreads();

        f32x16 acc00 = (f32x16)0.f, acc01 = (f32x16)0.f;
        f32x16 acc10 = (f32x16)0.f, acc11 = (f32x16)0.f;
#pragma unroll
        for (int ks = 0; ks < 9; ++ks) {
            short8 a0 = ldsA(As, (l & 31),      ks * 2 + (l >> 5));
            short8 a1 = ldsA(As, 32 + (l & 31), ks * 2 + (l >> 5));
            acc00 = __builtin_amdgcn_mfma_f32_32x32x16_bf16(a0, Bf[ks][0], acc00, 0, 0, 0);
            acc01 = __builtin_amdgcn_mfma_f32_32x32x16_bf16(a0, Bf[ks][1], acc01, 0, 0, 0);
            acc10 = __builtin_amdgcn_mfma_f32_32x32x16_bf16(a1, Bf[ks][0], acc10, 0, 0, 0);
            acc11 = __builtin_amdgcn_mfma_f32_32x32x16_bf16(a1, Bf[ks][1], acc11, 0, 0, 0);
        }

        // epilogue: s = x2w - 2 q.x = -2*acc
        const int half4 = (l >> 5) * 4;
        if (PASS == 1) {
            if (base + TILE_C <= segEnd) {
#pragma unroll
                for (int r = 0; r < 16; ++r) {
                    mn0 = fminf(mn0, fminf(-2.f * acc00[r], -2.f * acc10[r]));
                    mn1 = fminf(mn1, fminf(-2.f * acc01[r], -2.f * acc11[r]));
                }
            } else {
#pragma unroll
                for (int r = 0; r < 16; ++r) {
                    int row = (r & 3) + 8 * (r >> 2) + half4;
                    bool ok0 = (base + row) < segEnd;
                    bool ok1 = (base + 32 + row) < segEnd;
                    mn0 = fminf(mn0, fminf(ok0 ? -2.f * acc00[r] : INFINITY,
                                           ok1 ? -2.f * acc10[r] : INFINITY));
                    mn1 = fminf(mn1, fminf(ok0 ? -2.f * acc01[r] : INFINITY,
                                           ok1 ? -2.f * acc11[r] : INFINITY));
                }
            }
        } else {
#pragma unroll
            for (int r = 0; r < 16; ++r) {
                int row = (r & 3) + 8 * (r >> 2) + half4;
                int c0 = base + row, c1 = base + 32 + row;
                float s00 = -2.f * acc00[r], s10 = -2.f * acc10[r];
                float s01 = -2.f * acc01[r], s11 = -2.f * acc11[r];
                if (s00 <= tq0 && c0 < segEnd) emit_cand(q0,      c0, cnt, buf);
                if (s10 <= tq0 && c1 < segEnd) emit_cand(q0,      c1, cnt, buf);
                if (s01 <= tq1 && c0 < segEnd) emit_cand(q0 + 32, c0, cnt, buf);
                if (s11 <= tq1 && c1 < segEnd) emit_cand(q0 + 32, c1, cnt, buf);
            }
        }
    }

    if (PASS == 1) {
        size_t rowi = (size_t)(seg * 2 + (l >> 5)) * m;
        minbuf[rowi + q0]      = mn0;
        minbuf[rowi + q0 + 32] = mn1;
    }
}

// ---------- tau: 10th smallest of 128 stream-mins per query, + safety margin ----------
__global__ void tau_kernel(const float* __restrict__ minbuf, float* __restrict__ tau, int m) {
    int q = blockIdx.x * blockDim.x + threadIdx.x;
    if (q >= m) return;
    float ms[KTOP];
#pragma unroll
    for (int e = 0; e < KTOP; ++e) ms[e] = INFINITY;
    for (int i = 0; i < 2 * NSEG; ++i) {
        float v = minbuf[(size_t)i * m + q];
        if (v < ms[9]) {
            ms[9] = v;
#pragma unroll
            for (int p = 9; p > 0; --p) {
                float a = fminf(ms[p - 1], ms[p]);
                float b = fmaxf(ms[p - 1], ms[p]);
                ms[p - 1] = a; ms[p] = b;
            }
        }
    }
    tau[q] = ms[9] + DELTA;
}

// ---------- exact fp32 rescore of filtered candidates; top-10 + max act ----------
__global__ void rescore_kernel(const float* __restrict__ Xtf, const float* __restrict__ Xf,
                               const float* __restrict__ w, const float* __restrict__ x2wf,
                               const float* __restrict__ q2f, const int* __restrict__ cnt,
                               const int* __restrict__ buf, float* __restrict__ out, int m) {
    int q = blockIdx.x;
    int lane = threadIdx.x;  // 64
    float2 qv = ((const float2*)Xtf)[(size_t)q * 64 + lane];
    int c = min(cnt[q], CAP);
    float ls[KTOP], lw[KTOP];
#pragma unroll
    for (int e = 0; e < KTOP; ++e) { ls[e] = INFINITY; lw[e] = 0.f; }
    for (int i = 0; i < c; ++i) {
        int j = buf[q * CAP + i];
        float2 xv = ((const float2*)Xf)[(size_t)j * 64 + lane];
        float p = qv.x * xv.x + qv.y * xv.y;
#pragma unroll
        for (int o = 32; o; o >>= 1) p += __shfl_xor(p, o, 64);
        float s = x2wf[j] - 2.0f * p;           // identical in all lanes
        if (s < ls[9]) insert10(s, w[j], ls, lw);
    }
    if (lane == 0) {
        float q2v = q2f[q];
        float mx = -INFINITY;
#pragma unroll
        for (int e = 0; e < KTOP; ++e) {
            if (ls[e] < 1e30f) {
                float d2 = fmaxf(q2v + ls[e] + lw[e], 0.f);
                mx = fmaxf(mx, lw[e] - sqrtf(d2));
            }
        }
        out[q] = mx;
    }
}

// ---------- launch ----------
extern "C" void kernel_launch(void* const* d_in, const int* in_sizes, int n_in,
                              void* d_out, int out_size, void* d_ws, size_t ws_size,
                              hipStream_t stream) {
    const float* Xt = (const float*)d_in[0];
    const float* X  = (const float*)d_in[1];
    const float* w  = (const float*)d_in[2];
    const int m = in_sizes[0] / D;   // 2048
    const int n = in_sizes[1] / D;   // 100000

    auto align256 = [](size_t x) { return (x + 255) & ~(size_t)255; };
    char* p = (char*)d_ws;
    ushort* Xb   = (ushort*)p;  p += align256((size_t)n * D * 2);
    ushort* Xtb  = (ushort*)p;  p += align256((size_t)m * D * 2);
    uint*   x2p  = (uint*)p;    p += align256((size_t)n * 4);
    float*  x2wf = (float*)p;   p += align256((size_t)n * 4);
    float*  q2f  = (float*)p;   p += align256((size_t)m * 4);
    float*  minb = (float*)p;   p += align256((size_t)2 * NSEG * m * 4);
    float*  tau  = (float*)p;   p += align256((size_t)m * 4);
    int*    cnt  = (int*)p;     p += align256((size_t)m * 4);
    int*    buf  = (int*)p;     p += align256((size_t)m * CAP * 4);

    hipMemsetAsync(cnt, 0, (size_t)m * 4, stream);

    prep_kernel<<<(n + 3) / 4, 256, 0, stream>>>(X, w, Xb, x2p, x2wf, n, 1);
    prep_kernel<<<(m + 3) / 4, 256, 0, stream>>>(Xt, w, Xtb, nullptr, q2f, m, 0);

    dim3 grid(m / 256, NSEG);
    nd_pass<1><<<grid, 256, 0, stream>>>(Xb, Xtb, x2p, tau, minb, cnt, buf, m, n);
    tau_kernel<<<(m + 255) / 256, 256, 0, stream>>>(minb, tau, m);
    nd_pass<2><<<grid, 256, 0, stream>>>(Xb, Xtb, x2p, tau, minb, cnt, buf, m, n);
    rescore_kernel<<<m, 64, 0, stream>>>(Xt, X, w, x2wf, q2f, cnt, buf, (float*)d_out, m);
}